// Round 4
// baseline (6755.369 us; speedup 1.0000x reference)
//
#include <hip/hip_runtime.h>

#define LSEQ 2048
#define TAGS 12

__device__ __forceinline__ float sigm(float x){ return 1.0f/(1.0f+expf(-x)); }

// K0: zero exchange-tag buffer + diagnostic sentinels in d_out (overwritten by viterbi).
__global__ void init_kernel(unsigned long long* ex, float* outp)
{
  int tid = blockIdx.x*256 + threadIdx.x;
  if (tid < 1024) ex[tid] = 0ull;           // tag 0 never matches s+1 in [1,2048]
  if (tid == 0) outp[0] = 1.0f;
  if (tid < LSEQ) outp[1+tid] = 2.0f;
}

// K1: xg[d][t][row] = b_ih[row]+b_hh[row] + sum_e embed[sent[t]][e] * w_ih[row][e]
__global__ void xg_kernel(
    const int* sent, const float* embed,
    const float* w_ih_f, const float* b_ih_f, const float* b_hh_f,
    const float* w_ih_b, const float* b_ih_b, const float* b_hh_b,
    float* xg)
{
  __shared__ float x_sh[8][256];
  int tid = threadIdx.x;
  int t0 = blockIdx.x * 8;
  for (int i=0;i<8;++i){
    int idx = sent[t0+i];
    x_sh[i][tid] = embed[(size_t)idx*256 + tid];
  }
  __syncthreads();
  for (int ri=0; ri<8; ++ri){
    int r = ri*256 + tid;
    int d = r >> 10;
    int row = r & 1023;
    const float* wr = (d ? w_ih_b : w_ih_f) + (size_t)row*256;
    const float* bi = d ? b_ih_b : b_ih_f;
    const float* bh = d ? b_hh_b : b_hh_f;
    float acc[8];
    #pragma unroll
    for (int i=0;i<8;++i) acc[i]=0.f;
    for (int k0=0;k0<256;k0+=4){
      float4 p = *(const float4*)(wr + k0);
      #pragma unroll
      for (int i=0;i<8;++i){
        acc[i] += p.x*x_sh[i][k0] + p.y*x_sh[i][k0+1]
                + p.z*x_sh[i][k0+2] + p.w*x_sh[i][k0+3];
      }
    }
    float bias = bi[row] + bh[row];
    #pragma unroll
    for (int i=0;i<8;++i)
      xg[((size_t)d*LSEQ + (size_t)(t0+i))*1024 + row] = acc[i] + bias;
  }
}

// K2: sequential bidirectional LSTM recurrence.
// 8 blocks: blk>>2 = dir, blk&3 = quad (owns h[64q..64q+63] and its 4*64 gate rows).
// W_hh rows live in VGPRs. h broadcast via LDS; cross-block h exchange via
// (tag<<32 | float_bits) 64-bit device-scope atomics, parity double-buffered.
__global__ __launch_bounds__(256,1) void lstm_rec(
    const float* w_hh_f, const float* w_hh_b,
    const float* xg, float* hst, unsigned long long* ex)
{
  int blk = blockIdx.x;
  int d = blk >> 2, q = blk & 3;
  int tid = threadIdx.x;
  int g = tid >> 6, lane = tid & 63;
  int j = q*64 + lane;          // h index owned by wave-0 lane
  int row = g*256 + j;          // gate row (PyTorch gate order i,f,g,o)
  const float* W = d ? w_hh_b : w_hh_f;
  const float* xgd = xg + (size_t)d*LSEQ*1024;
  float* hd = hst + (size_t)d*LSEQ*256;
  unsigned long long* exd = ex + (size_t)d*512;

  __shared__ float h_sh[256];
  __shared__ float gate_sh[256];

  float w[256];
  {
    const float* wr = W + (size_t)row*256;
    #pragma unroll
    for (int k0=0;k0<256;k0+=4){
      float4 p = *(const float4*)(wr+k0);
      w[k0]=p.x; w[k0+1]=p.y; w[k0+2]=p.z; w[k0+3]=p.w;
    }
  }
  h_sh[tid] = 0.f;
  float c = 0.f;
  __syncthreads();

  int tfirst = d ? (LSEQ-1) : 0;
  float xgn = xgd[(size_t)tfirst*1024 + row];

  for (int s=0;s<LSEQ;++s){
    int t = d ? (LSEQ-1-s) : s;
    float a0=0.f,a1=0.f,a2=0.f,a3=0.f;
    #pragma unroll
    for (int k=0;k<256;k+=4){
      float4 h4 = *(const float4*)&h_sh[k];   // uniform addr -> broadcast ds_read_b128
      a0 += w[k]*h4.x; a1 += w[k+1]*h4.y; a2 += w[k+2]*h4.z; a3 += w[k+3]*h4.w;
    }
    float pre = xgn + ((a0+a1)+(a2+a3));
    if (s+1 < LSEQ){
      int tn = d ? (LSEQ-2-s) : (s+1);
      xgn = xgd[(size_t)tn*1024 + row];        // prefetch next step's xg
    }
    float act = (g==2) ? tanhf(pre) : sigm(pre);
    gate_sh[tid] = act;
    __syncthreads();
    if (g==0){
      float iv=gate_sh[lane], fv=gate_sh[64+lane], gv=gate_sh[128+lane], ov=gate_sh[192+lane];
      c = fv*c + iv*gv;
      float hn = ov * tanhf(c);
      h_sh[j] = hn;
      hd[(size_t)t*256 + j] = hn;
      unsigned long long pk =
          ((unsigned long long)(unsigned int)(s+1) << 32) |
          (unsigned long long)__float_as_uint(hn);
      atomicExch(&exd[((s&1)<<8)+j], pk);
    }
    __syncthreads();
    if (s+1 < LSEQ && tid < 192){
      int fq = tid >> 6;
      int qq = fq + (fq >= q ? 1 : 0);        // skip own quad
      int jf = qq*64 + (tid & 63);
      unsigned long long v;
      do { v = atomicAdd(&exd[((s&1)<<8)+jf], 0ull); }
      while ((unsigned int)(v>>32) != (unsigned int)(s+1));
      h_sh[jf] = __uint_as_float((unsigned int)v);
    }
    __syncthreads();
  }
}

// K3: feats[t][tag] = b_out[tag] + [hf|hb] . w_out[tag]
__global__ void feats_kernel(
    const float* hst, const float* w_out, const float* b_out,
    float* feats)
{
  __shared__ float w_sh[12*520];
  __shared__ float h_sh[16*520];
  int tid=threadIdx.x;
  int t0=blockIdx.x*16;
  for (int i=tid;i<12*512;i+=256){ int tag=i>>9,k=i&511; w_sh[tag*520+k]=w_out[i]; }
  for (int i=tid;i<16*512;i+=256){
    int tt=i>>9,k=i&511;
    float v = (k<256)? hst[(size_t)(t0+tt)*256+k] : hst[(size_t)(LSEQ+t0+tt)*256 + (k-256)];
    h_sh[tt*520+k]=v;
  }
  __syncthreads();
  if (tid<192){
    int tt=tid/12, tag=tid%12;
    const float* wr=&w_sh[tag*520];
    const float* hr=&h_sh[tt*520];
    float acc=b_out[tag];
    for (int k=0;k<512;k+=4){
      float4 a=*(const float4*)(wr+k);
      float4 b=*(const float4*)(hr+k);
      acc += a.x*b.x+a.y*b.y+a.z*b.z+a.w*b.w;
    }
    feats[(size_t)(t0+tt)*12+tag]=acc;
  }
}

// K4: Viterbi DP (12 lanes of one wave) + parallel backtrack.
__global__ void BiLSTM_CRF_14405320311361_kernel(
    const float* feats, const float* trans, float* outp)
{
  __shared__ unsigned char bps[LSEQ*12];   // bps[t][next] = best prev
  __shared__ float v_sh[16];
  __shared__ float term_sh[16];
  __shared__ int ibuf[66];                 // [0..63]=block entry tags, [64]=best terminal
  __shared__ unsigned char fmap[64*12];
  int lane = threadIdx.x;
  int next = (lane<12)? lane : 0;
  float tr[12];
  #pragma unroll
  for (int p=0;p<12;++p) tr[p]=trans[next*12+p];
  if (lane<12) v_sh[lane] = (lane==10)? 0.f : -10000.f;   // START=10
  __syncthreads();
  float fa=0.f, fb=0.f;
  if (lane<12){ fa=feats[lane]; fb=feats[12+lane]; }
  float vn=0.f;
  for (int t=0;t<LSEQ;++t){
    float4 va=*(const float4*)&v_sh[0];
    float4 vb=*(const float4*)&v_sh[4];
    float4 vc=*(const float4*)&v_sh[8];
    float best=tr[0]+va.x; int bp=0; float sc;
    sc=tr[1]+va.y;  if(sc>best){best=sc;bp=1;}
    sc=tr[2]+va.z;  if(sc>best){best=sc;bp=2;}
    sc=tr[3]+va.w;  if(sc>best){best=sc;bp=3;}
    sc=tr[4]+vb.x;  if(sc>best){best=sc;bp=4;}
    sc=tr[5]+vb.y;  if(sc>best){best=sc;bp=5;}
    sc=tr[6]+vb.z;  if(sc>best){best=sc;bp=6;}
    sc=tr[7]+vb.w;  if(sc>best){best=sc;bp=7;}
    sc=tr[8]+vc.x;  if(sc>best){best=sc;bp=8;}
    sc=tr[9]+vc.y;  if(sc>best){best=sc;bp=9;}
    sc=tr[10]+vc.z; if(sc>best){best=sc;bp=10;}
    sc=tr[11]+vc.w; if(sc>best){best=sc;bp=11;}
    vn = best + fa;
    fa = fb;
    if (lane<12 && t+2<LSEQ) fb = feats[(size_t)(t+2)*12+lane];
    if (lane<12){ v_sh[lane]=vn; bps[t*12+lane]=(unsigned char)bp; }
    // single wave: LDS ops issue in program order; compiler inserts lgkmcnt waits.
  }
  if (lane<12) term_sh[lane] = vn + trans[11*12+lane];   // STOP=11
  __syncthreads();
  if (lane==0){
    float bs=term_sh[0]; int bt=0;
    for (int p=1;p<12;++p){ if (term_sh[p]>bs){bs=term_sh[p];bt=p;} }
    outp[0] = bs;
    ibuf[64] = bt;
  }
  __syncthreads();
  // B1: each lane composes its 32-step block of backpointer maps
  {
    int b = lane;
    int f[12];
    int thi = b*32+31;
    #pragma unroll
    for (int x=0;x<12;++x) f[x] = bps[thi*12+x];
    for (int t=thi-1; t>=b*32; --t){
      int base = t*12;
      #pragma unroll
      for (int x=0;x<12;++x) f[x] = bps[base + f[x]];
    }
    #pragma unroll
    for (int x=0;x<12;++x) fmap[b*12+x] = (unsigned char)f[x];
  }
  __syncthreads();
  // B2: chain across the 64 blocks
  if (lane==0){
    int tag = ibuf[64];
    for (int b=63;b>=0;--b){ ibuf[b]=tag; tag = fmap[b*12+tag]; }
  }
  __syncthreads();
  // B3: re-walk blocks in parallel, emitting tags
  {
    int b = lane;
    int tag = ibuf[b];
    for (int t=b*32+31; t>=b*32; --t){
      outp[1+t] = (float)tag;
      tag = bps[t*12+tag];
    }
  }
}

extern "C" void kernel_launch(void* const* d_in, const int* in_sizes, int n_in,
                              void* d_out, int out_size, void* d_ws, size_t ws_size,
                              hipStream_t stream) {
  const int*   sent   = (const int*)d_in[0];
  const float* embed  = (const float*)d_in[1];
  const float* w_ih_f = (const float*)d_in[2];
  const float* w_hh_f = (const float*)d_in[3];
  const float* b_ih_f = (const float*)d_in[4];
  const float* b_hh_f = (const float*)d_in[5];
  const float* w_ih_b = (const float*)d_in[6];
  const float* w_hh_b = (const float*)d_in[7];
  const float* b_ih_b = (const float*)d_in[8];
  const float* b_hh_b = (const float*)d_in[9];
  const float* w_out  = (const float*)d_in[10];
  const float* b_out  = (const float*)d_in[11];
  const float* trans  = (const float*)d_in[12];

  float* xg   = (float*)d_ws;                                  // [2][L][1024] f32 = 16 MB
  float* hst  = xg + (size_t)2*LSEQ*1024;                      // [2][L][256]  f32 =  4 MB
  unsigned long long* ex = (unsigned long long*)(hst + (size_t)2*LSEQ*256); // 8 KB
  float* feats= (float*)(ex + 1024);                           // [L][12]      f32 = 96 KB
  float* outp = (float*)d_out;

  init_kernel<<<dim3(8), dim3(256), 0, stream>>>(ex, outp);
  xg_kernel<<<dim3(LSEQ/8), dim3(256), 0, stream>>>(
      sent, embed, w_ih_f, b_ih_f, b_hh_f, w_ih_b, b_ih_b, b_hh_b, xg);
  lstm_rec<<<dim3(8), dim3(256), 0, stream>>>(w_hh_f, w_hh_b, xg, hst, ex);
  feats_kernel<<<dim3(LSEQ/16), dim3(256), 0, stream>>>(hst, w_out, b_out, feats);
  BiLSTM_CRF_14405320311361_kernel<<<dim3(1), dim3(64), 0, stream>>>(feats, trans, outp);
}

// Round 5
// 4849.715 us; speedup vs baseline: 1.3929x; 1.3929x over previous
//
#include <hip/hip_runtime.h>

#define LSEQ 2048
#define TAGS 12

typedef _Float16 half2v __attribute__((ext_vector_type(2)));

__device__ __forceinline__ float sigm(float x){ return 1.0f/(1.0f+__expf(-x)); }
__device__ __forceinline__ float tanh_fast(float x){ return 1.0f - 2.0f/(1.0f+__expf(2.0f*x)); }

__device__ __forceinline__ half2v pack2(float a, float b){
  half2v r; r.x = (_Float16)a; r.y = (_Float16)b; return r;
}

// K0: zero exchange-tag buffer + diagnostic sentinels in d_out (overwritten by viterbi).
__global__ void init_kernel(unsigned long long* ex, float* outp)
{
  int tid = blockIdx.x*256 + threadIdx.x;
  if (tid < 1024) ex[tid] = 0ull;           // tag 0 never matches s+1 in [1,2048]
  if (tid == 0) outp[0] = 1.0f;
  if (tid < LSEQ) outp[1+tid] = 2.0f;
}

// K1: xg[d][t][row] = b_ih[row]+b_hh[row] + sum_e embed[sent[t]][e] * w_ih[row][e]
__global__ void xg_kernel(
    const int* sent, const float* embed,
    const float* w_ih_f, const float* b_ih_f, const float* b_hh_f,
    const float* w_ih_b, const float* b_ih_b, const float* b_hh_b,
    float* xg)
{
  __shared__ float x_sh[8][256];
  int tid = threadIdx.x;
  int t0 = blockIdx.x * 8;
  for (int i=0;i<8;++i){
    int idx = sent[t0+i];
    x_sh[i][tid] = embed[(size_t)idx*256 + tid];
  }
  __syncthreads();
  for (int ri=0; ri<8; ++ri){
    int r = ri*256 + tid;
    int d = r >> 10;
    int row = r & 1023;
    const float* wr = (d ? w_ih_b : w_ih_f) + (size_t)row*256;
    const float* bi = d ? b_ih_b : b_ih_f;
    const float* bh = d ? b_hh_b : b_hh_f;
    float acc[8];
    #pragma unroll
    for (int i=0;i<8;++i) acc[i]=0.f;
    for (int k0=0;k0<256;k0+=4){
      float4 p = *(const float4*)(wr + k0);
      #pragma unroll
      for (int i=0;i<8;++i){
        acc[i] += p.x*x_sh[i][k0] + p.y*x_sh[i][k0+1]
                + p.z*x_sh[i][k0+2] + p.w*x_sh[i][k0+3];
      }
    }
    float bias = bi[row] + bh[row];
    #pragma unroll
    for (int i=0;i<8;++i)
      xg[((size_t)d*LSEQ + (size_t)(t0+i))*1024 + row] = acc[i] + bias;
  }
}

// K2: sequential bidirectional LSTM recurrence, 2 CUs per direction.
// Active blocks: 0->(d0,c0) 8->(d0,c1) 1->(d1,c0) 9->(d1,c1); partners are
// blk and blk+8, which under round-robin XCD dispatch land on the SAME XCD.
// CU c owns units [128c,128c+128): all 4 gates. Thread (g=tid>>6, l=tid&63)
// computes rows g*256+128c+l and g*256+128c+64+l with f16-packed weights in
// VGPRs (fdot2, f32 accumulate). h lives as packed-f16 pairs: 1 pair per lane
// in VGPRs, broadcast via v_readlane (no LDS broadcast traffic). Cross-CU
// exchange: 64 (tag<<32 | h2bits) 64-bit atomics per step, parity dbuf.
__global__ __launch_bounds__(256,1) void lstm_rec(
    const float* w_hh_f, const float* w_hh_b,
    const float* xg, float* hst, unsigned long long* ex)
{
  int blk = blockIdx.x;
  int d, c;
  if      (blk == 0){ d=0; c=0; }
  else if (blk == 8){ d=0; c=1; }
  else if (blk == 1){ d=1; c=0; }
  else if (blk == 9){ d=1; c=1; }
  else return;

  int tid = threadIdx.x;
  int g = tid >> 6, l = tid & 63;
  int r0 = g*256 + 128*c + l;       // gate row (PyTorch order i,f,g,o)
  int r1 = r0 + 64;
  const float* W = d ? w_hh_b : w_hh_f;
  const float* xgd = xg + (size_t)d*LSEQ*1024;
  float* hd = hst + (size_t)d*LSEQ*256;
  unsigned long long* exd = ex + (size_t)d*256;

  __shared__ float gate_sh[512];      // [gate][128 local units]
  __shared__ unsigned h2_sh[128];     // packed f16 pair per global unit-pair

  // Load + convert weights: w0[k] = cols(2k,2k+1) of row r0 (pair k of h).
  half2v w0[128], w1[128];
  {
    const float* wr0 = W + (size_t)r0*256;
    const float* wr1 = W + (size_t)r1*256;
    #pragma unroll
    for (int k0=0;k0<64;++k0){
      float4 p = *(const float4*)(wr0 + 4*k0);
      w0[2*k0]   = pack2(p.x, p.y);
      w0[2*k0+1] = pack2(p.z, p.w);
      float4 q = *(const float4*)(wr1 + 4*k0);
      w1[2*k0]   = pack2(q.x, q.y);
      w1[2*k0+1] = pack2(q.z, q.w);
    }
  }
  if (tid < 128) h2_sh[tid] = 0u;     // h=0 (f16 pair 0x0)
  float c0 = 0.f, c1 = 0.f;           // cell state (only tid<64 uses)
  __syncthreads();

  int tfirst = d ? (LSEQ-1) : 0;
  float xg0 = xgd[(size_t)tfirst*1024 + r0];
  float xg1 = xgd[(size_t)tfirst*1024 + r1];

  for (int s=0;s<LSEQ;++s){
    int t = d ? (LSEQ-1-s) : s;
    // --- dot: gates = W_hh * h ---
    unsigned ha = h2_sh[l];           // pair l   (units 2l,2l+1)
    unsigned hb = h2_sh[64+l];        // pair 64+l
    float a0a = xg0, a0b = 0.f, a1a = xg1, a1b = 0.f;
    #pragma unroll
    for (int k=0;k<64;k+=2){
      unsigned pa = __builtin_amdgcn_readlane(ha, k);
      unsigned pb = __builtin_amdgcn_readlane(ha, k+1);
      half2v va = __builtin_bit_cast(half2v, pa);
      half2v vb = __builtin_bit_cast(half2v, pb);
      a0a = __builtin_amdgcn_fdot2(va, w0[k],   a0a, false);
      a1a = __builtin_amdgcn_fdot2(va, w1[k],   a1a, false);
      a0b = __builtin_amdgcn_fdot2(vb, w0[k+1], a0b, false);
      a1b = __builtin_amdgcn_fdot2(vb, w1[k+1], a1b, false);
    }
    #pragma unroll
    for (int k=0;k<64;k+=2){
      unsigned pa = __builtin_amdgcn_readlane(hb, k);
      unsigned pb = __builtin_amdgcn_readlane(hb, k+1);
      half2v va = __builtin_bit_cast(half2v, pa);
      half2v vb = __builtin_bit_cast(half2v, pb);
      a0a = __builtin_amdgcn_fdot2(va, w0[64+k],   a0a, false);
      a1a = __builtin_amdgcn_fdot2(va, w1[64+k],   a1a, false);
      a0b = __builtin_amdgcn_fdot2(vb, w0[64+k+1], a0b, false);
      a1b = __builtin_amdgcn_fdot2(vb, w1[64+k+1], a1b, false);
    }
    float pre0 = a0a + a0b;
    float pre1 = a1a + a1b;
    if (s+1 < LSEQ){
      int tn = d ? (LSEQ-2-s) : (s+1);
      xg0 = xgd[(size_t)tn*1024 + r0];   // prefetch next step
      xg1 = xgd[(size_t)tn*1024 + r1];
    }
    float act0, act1;
    if (g == 2){ act0 = tanh_fast(pre0); act1 = tanh_fast(pre1); }
    else       { act0 = sigm(pre0);      act1 = sigm(pre1); }
    gate_sh[g*128 + l]      = act0;
    gate_sh[g*128 + 64 + l] = act1;
    __syncthreads();

    // --- update (tid<64: units 128c+2m, 128c+2m+1) + send; (64..127): poll ---
    if (tid < 64){
      int m = tid;
      float2 gi = *(const float2*)&gate_sh[      2*m];
      float2 gf = *(const float2*)&gate_sh[128 + 2*m];
      float2 gg = *(const float2*)&gate_sh[256 + 2*m];
      float2 go = *(const float2*)&gate_sh[384 + 2*m];
      c0 = gf.x*c0 + gi.x*gg.x;
      c1 = gf.y*c1 + gi.y*gg.y;
      float h0 = go.x * tanh_fast(c0);
      float h1 = go.y * tanh_fast(c1);
      *(float2*)&hd[(size_t)t*256 + 128*c + 2*m] = make_float2(h0, h1);
      if (s+1 < LSEQ){
        unsigned hp = __builtin_bit_cast(unsigned, pack2(h0, h1));
        h2_sh[64*c + m] = hp;
        unsigned long long pk =
            ((unsigned long long)(unsigned)(s+1) << 32) | (unsigned long long)hp;
        atomicExch(&exd[((s&1)<<7) + 64*c + m], pk);
      }
    } else if (tid < 128 && s+1 < LSEQ){
      int m = tid - 64;
      int slot = 64*(1-c) + m;
      unsigned long long v;
      do { v = atomicAdd(&exd[((s&1)<<7) + slot], 0ull); }
      while ((unsigned)(v>>32) != (unsigned)(s+1));
      h2_sh[slot] = (unsigned)v;
    }
    __syncthreads();
  }
}

// K3: feats[t][tag] = b_out[tag] + [hf|hb] . w_out[tag]
__global__ void feats_kernel(
    const float* hst, const float* w_out, const float* b_out,
    float* feats)
{
  __shared__ float w_sh[12*520];
  __shared__ float h_sh[16*520];
  int tid=threadIdx.x;
  int t0=blockIdx.x*16;
  for (int i=tid;i<12*512;i+=256){ int tag=i>>9,k=i&511; w_sh[tag*520+k]=w_out[i]; }
  for (int i=tid;i<16*512;i+=256){
    int tt=i>>9,k=i&511;
    float v = (k<256)? hst[(size_t)(t0+tt)*256+k] : hst[(size_t)(LSEQ+t0+tt)*256 + (k-256)];
    h_sh[tt*520+k]=v;
  }
  __syncthreads();
  if (tid<192){
    int tt=tid/12, tag=tid%12;
    const float* wr=&w_sh[tag*520];
    const float* hr=&h_sh[tt*520];
    float acc=b_out[tag];
    for (int k=0;k<512;k+=4){
      float4 a=*(const float4*)(wr+k);
      float4 b=*(const float4*)(hr+k);
      acc += a.x*b.x+a.y*b.y+a.z*b.z+a.w*b.w;
    }
    feats[(size_t)(t0+tt)*12+tag]=acc;
  }
}

// K4: Viterbi DP (12 lanes of one wave) + parallel backtrack.
__global__ void BiLSTM_CRF_14405320311361_kernel(
    const float* feats, const float* trans, float* outp)
{
  __shared__ unsigned char bps[LSEQ*12];   // bps[t][next] = best prev
  __shared__ float v_sh[16];
  __shared__ float term_sh[16];
  __shared__ int ibuf[66];                 // [0..63]=block entry tags, [64]=best terminal
  __shared__ unsigned char fmap[64*12];
  int lane = threadIdx.x;
  int next = (lane<12)? lane : 0;
  float tr[12];
  #pragma unroll
  for (int p=0;p<12;++p) tr[p]=trans[next*12+p];
  if (lane<12) v_sh[lane] = (lane==10)? 0.f : -10000.f;   // START=10
  __syncthreads();
  float fa=0.f, fb=0.f;
  if (lane<12){ fa=feats[lane]; fb=feats[12+lane]; }
  float vn=0.f;
  for (int t=0;t<LSEQ;++t){
    float4 va=*(const float4*)&v_sh[0];
    float4 vb=*(const float4*)&v_sh[4];
    float4 vc=*(const float4*)&v_sh[8];
    float best=tr[0]+va.x; int bp=0; float sc;
    sc=tr[1]+va.y;  if(sc>best){best=sc;bp=1;}
    sc=tr[2]+va.z;  if(sc>best){best=sc;bp=2;}
    sc=tr[3]+va.w;  if(sc>best){best=sc;bp=3;}
    sc=tr[4]+vb.x;  if(sc>best){best=sc;bp=4;}
    sc=tr[5]+vb.y;  if(sc>best){best=sc;bp=5;}
    sc=tr[6]+vb.z;  if(sc>best){best=sc;bp=6;}
    sc=tr[7]+vb.w;  if(sc>best){best=sc;bp=7;}
    sc=tr[8]+vc.x;  if(sc>best){best=sc;bp=8;}
    sc=tr[9]+vc.y;  if(sc>best){best=sc;bp=9;}
    sc=tr[10]+vc.z; if(sc>best){best=sc;bp=10;}
    sc=tr[11]+vc.w; if(sc>best){best=sc;bp=11;}
    vn = best + fa;
    fa = fb;
    if (lane<12 && t+2<LSEQ) fb = feats[(size_t)(t+2)*12+lane];
    if (lane<12){ v_sh[lane]=vn; bps[t*12+lane]=(unsigned char)bp; }
  }
  if (lane<12) term_sh[lane] = vn + trans[11*12+lane];   // STOP=11
  __syncthreads();
  if (lane==0){
    float bs=term_sh[0]; int bt=0;
    for (int p=1;p<12;++p){ if (term_sh[p]>bs){bs=term_sh[p];bt=p;} }
    outp[0] = bs;
    ibuf[64] = bt;
  }
  __syncthreads();
  // B1: each lane composes its 32-step block of backpointer maps
  {
    int b = lane;
    int f[12];
    int thi = b*32+31;
    #pragma unroll
    for (int x=0;x<12;++x) f[x] = bps[thi*12+x];
    for (int t=thi-1; t>=b*32; --t){
      int base = t*12;
      #pragma unroll
      for (int x=0;x<12;++x) f[x] = bps[base + f[x]];
    }
    #pragma unroll
    for (int x=0;x<12;++x) fmap[b*12+x] = (unsigned char)f[x];
  }
  __syncthreads();
  // B2: chain across the 64 blocks
  if (lane==0){
    int tag = ibuf[64];
    for (int b=63;b>=0;--b){ ibuf[b]=tag; tag = fmap[b*12+tag]; }
  }
  __syncthreads();
  // B3: re-walk blocks in parallel, emitting tags
  {
    int b = lane;
    int tag = ibuf[b];
    for (int t=b*32+31; t>=b*32; --t){
      outp[1+t] = (float)tag;
      tag = bps[t*12+tag];
    }
  }
}

extern "C" void kernel_launch(void* const* d_in, const int* in_sizes, int n_in,
                              void* d_out, int out_size, void* d_ws, size_t ws_size,
                              hipStream_t stream) {
  const int*   sent   = (const int*)d_in[0];
  const float* embed  = (const float*)d_in[1];
  const float* w_ih_f = (const float*)d_in[2];
  const float* w_hh_f = (const float*)d_in[3];
  const float* b_ih_f = (const float*)d_in[4];
  const float* b_hh_f = (const float*)d_in[5];
  const float* w_ih_b = (const float*)d_in[6];
  const float* w_hh_b = (const float*)d_in[7];
  const float* b_ih_b = (const float*)d_in[8];
  const float* b_hh_b = (const float*)d_in[9];
  const float* w_out  = (const float*)d_in[10];
  const float* b_out  = (const float*)d_in[11];
  const float* trans  = (const float*)d_in[12];

  float* xg   = (float*)d_ws;                                  // [2][L][1024] f32 = 16 MB
  float* hst  = xg + (size_t)2*LSEQ*1024;                      // [2][L][256]  f32 =  4 MB
  unsigned long long* ex = (unsigned long long*)(hst + (size_t)2*LSEQ*256); // 8 KB
  float* feats= (float*)(ex + 1024);                           // [L][12]      f32 = 96 KB
  float* outp = (float*)d_out;

  init_kernel<<<dim3(8), dim3(256), 0, stream>>>(ex, outp);
  xg_kernel<<<dim3(LSEQ/8), dim3(256), 0, stream>>>(
      sent, embed, w_ih_f, b_ih_f, b_hh_f, w_ih_b, b_ih_b, b_hh_b, xg);
  lstm_rec<<<dim3(16), dim3(256), 0, stream>>>(w_hh_f, w_hh_b, xg, hst, ex);
  feats_kernel<<<dim3(LSEQ/16), dim3(256), 0, stream>>>(hst, w_out, b_out, feats);
  BiLSTM_CRF_14405320311361_kernel<<<dim3(1), dim3(64), 0, stream>>>(feats, trans, outp);
}